// Round 7
// baseline (347.872 us; speedup 1.0000x reference)
//
#include <hip/hip_runtime.h>

typedef __attribute__((ext_vector_type(8))) short short8;
typedef __attribute__((ext_vector_type(4))) float f32x4;
typedef unsigned short ushort_t;
typedef unsigned int uint_t;

#define SEQ 4096
#define NB 4
#define EMB 1024
#define HD 128

__device__ __forceinline__ ushort_t f2bf(float f) {
  uint_t u = __float_as_uint(f);
  u += 0x7fffu + ((u >> 16) & 1u);
  return (ushort_t)(u >> 16);
}
__device__ __forceinline__ float bf2f(ushort_t h) {
  return __uint_as_float(((uint_t)h) << 16);
}

// DPP row_ror butterfly over the 16-lane row (matches our lg-groups exactly).
// Full-rate VALU ops; replaces ds_bpermute-based __shfl_xor (LDS pipe, ~40cyc).
template <int CTRL>
__device__ __forceinline__ float dpp_mov(float x) {
  return __int_as_float(__builtin_amdgcn_update_dpp(
      __float_as_int(x), __float_as_int(x), CTRL, 0xf, 0xf, false));
}
__device__ __forceinline__ float rmax16(float x) {
  x = fmaxf(x, dpp_mov<0x128>(x));  // row_ror:8
  x = fmaxf(x, dpp_mov<0x124>(x));  // row_ror:4
  x = fmaxf(x, dpp_mov<0x122>(x));  // row_ror:2
  x = fmaxf(x, dpp_mov<0x121>(x));  // row_ror:1
  return x;
}
__device__ __forceinline__ float rsum16(float x) {
  x += dpp_mov<0x128>(x);
  x += dpp_mov<0x124>(x);
  x += dpp_mov<0x122>(x);
  x += dpp_mov<0x121>(x);
  return x;
}

// -------------------- Kernel 0: weight prep --------------------
// Wt2 layout: [kc 16][n 384][64 k-els], K-panelized AND pre-swizzled:
// within row n, physical granule p holds logical granule g = p ^ (n&7).
__global__ __launch_bounds__(256) void wt_prep(const float* __restrict__ Wq,
                                               const float* __restrict__ Wk,
                                               const float* __restrict__ Wv,
                                               ushort_t* __restrict__ Wt2) {
  int idx = blockIdx.x * 256 + threadIdx.x;  // [0, 393216)
  int kc = idx / 24576;
  int rem = idx - kc * 24576;
  int n = rem >> 6;
  int p = (rem >> 3) & 7;
  int e = rem & 7;
  int g = p ^ (n & 7);
  int k = kc * 64 + g * 8 + e;
  int o = n >> 7, nn = n & 127;
  const float* W = (o == 0) ? Wq : ((o == 1) ? Wk : Wv);
  Wt2[idx] = f2bf(W[k * 128 + nn]);
}

// -------------------- Kernel 1: fused QKV projection (LDS-staged GEMM) ------
// 512 blocks x 512 thr. Block = 32 x-rows, all 384 cols, BK=64.
// T14 prefetch: next kc's A/B staged to regs during compute of current kc.
__global__ __launch_bounds__(512, 4) void proj(const float* __restrict__ x,
                                               const ushort_t* __restrict__ Wt2,
                                               ushort_t* __restrict__ qb,
                                               ushort_t* __restrict__ kb,
                                               ushort_t* __restrict__ vt) {
  __shared__ __align__(16) ushort_t ldsA[32 * 64];   // 4 KB, XOR-swizzled granules
  __shared__ __align__(16) ushort_t ldsB[384 * 64];  // 48 KB, linear (pre-swizzled)
  int m0 = blockIdx.x * 32;
  int tid = threadIdx.x;
  int w = tid >> 6, l = tid & 63, l15 = l & 15, lg = l >> 4;

  f32x4 acc[2][3];
#pragma unroll
  for (int mf = 0; mf < 2; ++mf)
#pragma unroll
    for (int f = 0; f < 3; ++f) acc[mf][f] = (f32x4){0.f, 0.f, 0.f, 0.f};

  int arow = tid >> 4;
  int asub = tid & 15;
  const float* xsrc = x + (size_t)(m0 + arow) * 1024 + asub * 4;
  ushort_t* adst = ldsA + arow * 64 + ((((asub >> 1) ^ (arow & 7)) << 3) | ((asub & 1) << 2));

  // prologue prefetch (kc=0)
  float4 xa = *(const float4*)(xsrc);
  uint4 bpre[6];
#pragma unroll
  for (int j2 = 0; j2 < 6; ++j2)
    bpre[j2] = *(const uint4*)(Wt2 + (j2 * 512 + tid) * 8);

  for (int kc = 0; kc < 16; ++kc) {
    // commit staged regs to LDS
    uint2 aw;
    aw.x = (uint_t)f2bf(xa.x) | ((uint_t)f2bf(xa.y) << 16);
    aw.y = (uint_t)f2bf(xa.z) | ((uint_t)f2bf(xa.w) << 16);
    *(uint2*)adst = aw;
#pragma unroll
    for (int j2 = 0; j2 < 6; ++j2)
      *(uint4*)(ldsB + (j2 * 512 + tid) * 8) = bpre[j2];
    __syncthreads();
    // prefetch next kc (latency hides under compute below)
    if (kc + 1 < 16) {
      xa = *(const float4*)(xsrc + (kc + 1) * 64);
      const ushort_t* bsrc = Wt2 + (kc + 1) * 24576;
#pragma unroll
      for (int j2 = 0; j2 < 6; ++j2)
        bpre[j2] = *(const uint4*)(bsrc + (j2 * 512 + tid) * 8);
    }
#pragma unroll
    for (int c = 0; c < 2; ++c) {
      int g = c * 4 + lg;
      short8 af[2];
#pragma unroll
      for (int mf = 0; mf < 2; ++mf) {
        int r = mf * 16 + l15;
        af[mf] = *(const short8*)(ldsA + r * 64 + ((g ^ (r & 7)) << 3));
      }
#pragma unroll
      for (int f = 0; f < 3; ++f) {
        int n = w * 48 + f * 16 + l15;
        short8 bf = *(const short8*)(ldsB + n * 64 + ((g ^ (n & 7)) << 3));
        acc[0][f] = __builtin_amdgcn_mfma_f32_16x16x32_bf16(af[0], bf, acc[0][f], 0, 0, 0);
        acc[1][f] = __builtin_amdgcn_mfma_f32_16x16x32_bf16(af[1], bf, acc[1][f], 0, 0, 0);
      }
    }
    __syncthreads();
  }

  // epilogue: C layout col = l15, row = lg*4 + j
#pragma unroll
  for (int f = 0; f < 3; ++f) {
    int cg = w * 48 + f * 16 + l15;  // [0,384)
    int o = cg >> 7, col = cg & 127;
#pragma unroll
    for (int mf = 0; mf < 2; ++mf)
#pragma unroll
      for (int j = 0; j < 4; ++j) {
        int row = m0 + mf * 16 + lg * 4 + j;
        float vv = acc[mf][f][j];
        if (o == 0) {
          qb[(size_t)row * 128 + col] = f2bf(vv * 0.03125f);
        } else if (o == 1) {
          kb[(size_t)row * 128 + col] = f2bf(vv);
        } else {
          vt[((size_t)((row >> 12) * 128 + col)) * 4096 + (row & 4095)] = f2bf(vv);
        }
      }
  }
}

// -------------------- Kernel 2: sliced causal flash attention --------------------
// r4 structure + (a) T14 reg-prefetch of next unit, (b) DPP row_ror reduces,
// (c) defer-max THR=8 (skip accO rescale when no significant new max).
__global__ __launch_bounds__(256, 2) void attn_slice(const ushort_t* __restrict__ qb,
                                                     const ushort_t* __restrict__ kb,
                                                     const ushort_t* __restrict__ vt,
                                                     ushort_t* __restrict__ pO,
                                                     float* __restrict__ pML) {
  __shared__ __align__(16) ushort_t ldsK[64][128];   // granule g^=r&15
  __shared__ __align__(16) ushort_t ldsV[128][64];   // granule g^=r&7 (V^T)
  __shared__ __align__(16) ushort_t ldsP[4][32][64]; // per-wave P, g^=row&7

  int bid = blockIdx.x;
  int e = 143 - (bid >> 2);  // heavy entries first
  int b = bid & 3;
  int s = 0, j = 0, base = 0;
#pragma unroll
  for (int g = 0; g < 8; ++g) {
    int sz = 4 * (g + 1);
    if (e < base + sz) {
      int r = e - base;
      s = 4 * g + r / (g + 1);
      j = r % (g + 1);
      break;
    }
    base += sz;
  }
  int nt = 2 * s + 2, ns = (s >> 2) + 1;
  int u0 = j * nt / ns, u1 = (j + 1) * nt / ns;

  int tid = threadIdx.x, w = tid >> 6, l = tid & 63, l15 = l & 15, lg = l >> 4;
  int r0w = 128 * s + 32 * w;

  const ushort_t* qp = qb + (size_t)(b * 4096 + r0w + l15) * 128;
  short8 aq[2][4];
#pragma unroll
  for (int h = 0; h < 2; ++h)
#pragma unroll
    for (int c = 0; c < 4; ++c) aq[h][c] = *(const short8*)(qp + h * 2048 + c * 32 + lg * 8);

  f32x4 accO[2][8];
#pragma unroll
  for (int h = 0; h < 2; ++h)
#pragma unroll
    for (int i = 0; i < 8; ++i) accO[h][i] = (f32x4){0.f, 0.f, 0.f, 0.f};
  float m[2][4], lsum[2][4];
#pragma unroll
  for (int h = 0; h < 2; ++h)
#pragma unroll
    for (int jj = 0; jj < 4; ++jj) { m[h][jj] = -1e30f; lsum[h][jj] = 0.f; }

  uint4 kpre[4], vpre[4];
  auto load_unit = [&](int u) {
    const ushort_t* ksrc = kb + ((size_t)b * 4096 + u * 64) * 128;
#pragma unroll
    for (int i = 0; i < 4; ++i) {
      int d = i * 256 + tid;
      kpre[i] = *(const uint4*)(ksrc + (d >> 4) * 128 + (d & 15) * 8);
    }
    const ushort_t* vsrc = vt + (size_t)b * 524288 + u * 64;
#pragma unroll
    for (int i = 0; i < 4; ++i) {
      int d = i * 256 + tid;
      vpre[i] = *(const uint4*)(vsrc + (size_t)(d >> 3) * 4096 + (d & 7) * 8);
    }
  };

  load_unit(u0);
  for (int u = u0; u < u1; ++u) {
    // commit staged regs to swizzled LDS
#pragma unroll
    for (int i = 0; i < 4; ++i) {
      int d = i * 256 + tid;
      int r = d >> 4, g = d & 15;
      *(uint4*)&ldsK[r][(g ^ (r & 15)) * 8] = kpre[i];
      int rv = d >> 3, gv = d & 7;
      *(uint4*)&ldsV[rv][(gv ^ (rv & 7)) * 8] = vpre[i];
    }
    __syncthreads();
    if (u + 1 < u1) load_unit(u + 1);  // latency hides under compute below
    bool skip = (64 * u > r0w + 31);
    if (!skip) {
      f32x4 s_[2][4];
#pragma unroll
      for (int h = 0; h < 2; ++h)
#pragma unroll
        for (int fi = 0; fi < 4; ++fi) s_[h][fi] = (f32x4){0.f, 0.f, 0.f, 0.f};
#pragma unroll
      for (int c = 0; c < 4; ++c)
#pragma unroll
        for (int fi = 0; fi < 4; ++fi) {
          short8 bk = *(const short8*)&ldsK[fi * 16 + l15][((c * 4 + lg) ^ l15) * 8];
          s_[0][fi] = __builtin_amdgcn_mfma_f32_16x16x32_bf16(aq[0][c], bk, s_[0][fi], 0, 0, 0);
          s_[1][fi] = __builtin_amdgcn_mfma_f32_16x16x32_bf16(aq[1][c], bk, s_[1][fi], 0, 0, 0);
        }
      if (64 * u + 63 > r0w) {
#pragma unroll
        for (int h = 0; h < 2; ++h)
#pragma unroll
          for (int fi = 0; fi < 4; ++fi) {
            int key = 64 * u + fi * 16 + l15;
#pragma unroll
            for (int jj = 0; jj < 4; ++jj)
              if (key > r0w + h * 16 + lg * 4 + jj) s_[h][fi][jj] = -__builtin_inff();
          }
      }
      // tile row-max via in-reg + DPP
      float tm[2][4];
#pragma unroll
      for (int h = 0; h < 2; ++h)
#pragma unroll
        for (int jj = 0; jj < 4; ++jj) {
          float t = fmaxf(fmaxf(s_[h][0][jj], s_[h][1][jj]), fmaxf(s_[h][2][jj], s_[h][3][jj]));
          tm[h][jj] = rmax16(t);
        }
      // defer-max: skip rescale when no row grew its max by > 8
      bool dfr = true;
#pragma unroll
      for (int h = 0; h < 2; ++h)
#pragma unroll
        for (int jj = 0; jj < 4; ++jj) dfr = dfr && (tm[h][jj] <= m[h][jj] + 8.0f);
      bool rescale = !__all(dfr);
      float mn[2][4], sc[2][4];
      if (rescale) {
#pragma unroll
        for (int h = 0; h < 2; ++h)
#pragma unroll
          for (int jj = 0; jj < 4; ++jj) {
            mn[h][jj] = fmaxf(m[h][jj], tm[h][jj]);
            sc[h][jj] = __expf(m[h][jj] - mn[h][jj]);
          }
      } else {
#pragma unroll
        for (int h = 0; h < 2; ++h)
#pragma unroll
          for (int jj = 0; jj < 4; ++jj) { mn[h][jj] = m[h][jj]; sc[h][jj] = 1.0f; }
      }
      float rs[2][4];
#pragma unroll
      for (int h = 0; h < 2; ++h)
#pragma unroll
        for (int jj = 0; jj < 4; ++jj) rs[h][jj] = 0.f;
#pragma unroll
      for (int h = 0; h < 2; ++h)
#pragma unroll
        for (int fi = 0; fi < 4; ++fi)
#pragma unroll
          for (int jj = 0; jj < 4; ++jj) {
            float p = __expf(s_[h][fi][jj] - mn[h][jj]);
            s_[h][fi][jj] = p;
            rs[h][jj] += p;
          }
#pragma unroll
      for (int h = 0; h < 2; ++h)
#pragma unroll
        for (int jj = 0; jj < 4; ++jj) {
          rs[h][jj] = rsum16(rs[h][jj]);
          lsum[h][jj] = lsum[h][jj] * sc[h][jj] + rs[h][jj];
          m[h][jj] = mn[h][jj];
        }
      if (rescale) {
#pragma unroll
        for (int h = 0; h < 2; ++h)
#pragma unroll
          for (int f = 0; f < 8; ++f)
#pragma unroll
            for (int jj = 0; jj < 4; ++jj) accO[h][f][jj] *= sc[h][jj];
      }
      // P -> LDS (swizzled) -> A frags
#pragma unroll
      for (int h = 0; h < 2; ++h)
#pragma unroll
        for (int fi = 0; fi < 4; ++fi)
#pragma unroll
          for (int jj = 0; jj < 4; ++jj) {
            int row = h * 16 + lg * 4 + jj;
            int gidx = fi * 2 + (l15 >> 3);
            ldsP[w][row][((gidx ^ (row & 7)) << 3) | (l15 & 7)] = f2bf(s_[h][fi][jj]);
          }
      short8 ap[2][2];
#pragma unroll
      for (int h = 0; h < 2; ++h)
#pragma unroll
        for (int c = 0; c < 2; ++c)
          ap[h][c] = *(const short8*)&ldsP[w][h * 16 + l15][((c * 4 + lg) ^ (l15 & 7)) * 8];
#pragma unroll
      for (int c = 0; c < 2; ++c)
#pragma unroll
        for (int f = 0; f < 8; ++f) {
          short8 bv = *(const short8*)&ldsV[f * 16 + l15][((c * 4 + lg) ^ (l15 & 7)) * 8];
          accO[0][f] = __builtin_amdgcn_mfma_f32_16x16x32_bf16(ap[0][c], bv, accO[0][f], 0, 0, 0);
          accO[1][f] = __builtin_amdgcn_mfma_f32_16x16x32_bf16(ap[1][c], bv, accO[1][f], 0, 0, 0);
        }
    }
    __syncthreads();
  }

  size_t obase = (size_t)bid * 16384;
#pragma unroll
  for (int h = 0; h < 2; ++h)
#pragma unroll
    for (int f = 0; f < 8; ++f)
#pragma unroll
      for (int jj = 0; jj < 4; ++jj) {
        int row = w * 32 + h * 16 + lg * 4 + jj;
        pO[obase + (size_t)row * 128 + f * 16 + l15] = f2bf(accO[h][f][jj]);
      }
  if (l15 == 0) {
#pragma unroll
    for (int h = 0; h < 2; ++h)
#pragma unroll
      for (int jj = 0; jj < 4; ++jj) {
        int row = w * 32 + h * 16 + lg * 4 + jj;
        pML[(size_t)bid * 256 + row * 2 + 0] = m[h][jj];
        pML[(size_t)bid * 256 + row * 2 + 1] = lsum[h][jj];
      }
  }
}

// -------------------- Kernel 3: merge split-K partials --------------------
__global__ __launch_bounds__(256) void attn_merge(const ushort_t* __restrict__ pO,
                                                  const float* __restrict__ pML,
                                                  float* __restrict__ out) {
  int idx = blockIdx.x * 256 + threadIdx.x;  // 524288 threads
  int row = idx >> 5;
  int cg = (idx & 31) * 4;
  int b = row >> 12, sr = row & 4095;
  int s = sr >> 7, g = s >> 2, ns = g + 1;
  int cumS = (g + 1) * (s - 2 * g);
  int rr = sr & 127;
  float M = -1e30f;
  for (int j = 0; j < ns; ++j) {
    int gid = (143 - (cumS + j)) * 4 + b;
    M = fmaxf(M, pML[(size_t)gid * 256 + rr * 2 + 0]);
  }
  float L = 0.f;
  float o0 = 0.f, o1 = 0.f, o2 = 0.f, o3 = 0.f;
  for (int j = 0; j < ns; ++j) {
    int gid = (143 - (cumS + j)) * 4 + b;
    float mv = pML[(size_t)gid * 256 + rr * 2 + 0];
    float lv = pML[(size_t)gid * 256 + rr * 2 + 1];
    float coef = __expf(mv - M);
    L += lv * coef;
    const ushort_t* op = pO + (size_t)gid * 16384 + rr * 128 + cg;
    uint2 pv = *(const uint2*)op;
    o0 += coef * bf2f((ushort_t)(pv.x & 0xffff));
    o1 += coef * bf2f((ushort_t)(pv.x >> 16));
    o2 += coef * bf2f((ushort_t)(pv.y & 0xffff));
    o3 += coef * bf2f((ushort_t)(pv.y >> 16));
  }
  float inv = 1.0f / L;
  float4 r = {o0 * inv, o1 * inv, o2 * inv, o3 * inv};
  *(float4*)(out + (size_t)row * 128 + cg) = r;
}

// -------------------- launch --------------------
extern "C" void kernel_launch(void* const* d_in, const int* in_sizes, int n_in,
                              void* d_out, int out_size, void* d_ws, size_t ws_size,
                              hipStream_t stream) {
  const float* x = (const float*)d_in[0];
  const float* Wk = (const float*)d_in[1];
  const float* Wq = (const float*)d_in[2];
  const float* Wv = (const float*)d_in[3];
  float* out = (float*)d_out;
  char* ws = (char*)d_ws;
  ushort_t* Wt2 = (ushort_t*)(ws);                        // 768 KB
  ushort_t* qb = (ushort_t*)(ws + 786432);                // 4 MB
  ushort_t* kbp = (ushort_t*)(ws + 786432 + 4194304);     // 4 MB
  ushort_t* vt = (ushort_t*)(ws + 786432 + 8388608);      // 4 MB
  ushort_t* pO = (ushort_t*)(ws + 13369344);              // 18.87 MB
  float* pML = (float*)(ws + 32243712);                   // 0.59 MB

  hipLaunchKernelGGL(wt_prep, dim3(1536), dim3(256), 0, stream, Wq, Wk, Wv, Wt2);
  hipLaunchKernelGGL(proj, dim3(512), dim3(512), 0, stream, x, Wt2, qb, kbp, vt);
  hipLaunchKernelGGL(attn_slice, dim3(576), dim3(256), 0, stream, qb, kbp, vt, pO, pML);
  hipLaunchKernelGGL(attn_merge, dim3(2048), dim3(256), 0, stream, pO, pML, out);
}